// Round 4
// baseline (2984.768 us; speedup 1.0000x reference)
//
#include <hip/hip_runtime.h>

#define FD 64           // feature dim D = A = G = 64
#define NSLOPE 0.01f
#define SCAN_BS 1024

__device__ __forceinline__ float lrelu(float v) { return v > 0.f ? v : NSLOPE * v; }

__device__ __forceinline__ unsigned enc_f32(float f) {
    unsigned u = __float_as_uint(f);
    return (u & 0x80000000u) ? ~u : (u | 0x80000000u);
}
__device__ __forceinline__ float dec_f32(unsigned u) {
    return (u & 0x80000000u) ? __uint_as_float(u & 0x7FFFFFFFu) : __uint_as_float(~u);
}

// ---------------- preprocessing: CSR by dst (once per launch) ----------------

__global__ void k_hist(const int* __restrict__ dst, int* __restrict__ deg, int E)
{
    int e = blockIdx.x * blockDim.x + threadIdx.x;
    if (e < E) atomicAdd(&deg[dst[e]], 1);
}

__global__ void k_scan1(const int* __restrict__ deg, int* __restrict__ off,
                        int* __restrict__ bsums, int N)
{
    __shared__ int tmp[SCAN_BS];
    int t = threadIdx.x, b = blockIdx.x;
    int i = b * SCAN_BS + t;
    int v = (i < N) ? deg[i] : 0;
    tmp[t] = v;
    __syncthreads();
    for (int d = 1; d < SCAN_BS; d <<= 1) {
        int add = (t >= d) ? tmp[t - d] : 0;
        __syncthreads();
        tmp[t] += add;
        __syncthreads();
    }
    if (i < N) off[i] = tmp[t] - v;
    if (t == SCAN_BS - 1) bsums[b] = tmp[t];
}

__global__ void k_scan2(int* __restrict__ bsums, int nb)
{
    __shared__ int tmp[SCAN_BS];
    int t = threadIdx.x;
    int v = (t < nb) ? bsums[t] : 0;
    tmp[t] = v;
    __syncthreads();
    for (int d = 1; d < SCAN_BS; d <<= 1) {
        int add = (t >= d) ? tmp[t - d] : 0;
        __syncthreads();
        tmp[t] += add;
        __syncthreads();
    }
    if (t < nb) bsums[t] = tmp[t] - v;
}

__global__ void k_scan3(int* __restrict__ off, const int* __restrict__ bsums,
                        int* __restrict__ cursor, int N)
{
    int i = blockIdx.x * blockDim.x + threadIdx.x;
    if (i < N) {
        int o = off[i] + bsums[i >> 10];
        off[i] = o;
        cursor[i] = o;
    }
}

__global__ void k_place(const int* __restrict__ src, const int* __restrict__ dst,
                        int* __restrict__ cursor, int* __restrict__ esrc, int E)
{
    int e = blockIdx.x * blockDim.x + threadIdx.x;
    if (e >= E) return;
    int pos = atomicAdd(&cursor[dst[e]], 1);
    esrc[pos] = src[e];
}

// ---------------- per-step kernels ----------------

// K1: p = x @ Wm + bm  — LDS-tiled GEMM, 64x64 tile per 256-thread block
__global__ void k_proj(const float* __restrict__ x, const float* __restrict__ Wm,
                       const float* __restrict__ bm, float* __restrict__ p, int N)
{
    __shared__ float At[16][68];   // A^T: At[k][m]
    __shared__ float Bt[16][64];   // Bt[k][j]
    const int tid = threadIdx.x;
    const int tr = tid >> 4, tc = tid & 15;        // 16x16 thread grid
    const int n0 = blockIdx.x * 64;

    const int ms = tid >> 2, qs = tid & 3;         // staging coords: row, k-quad
    const int rowc = min(n0 + ms, N - 1);
    const float* arow = x + (size_t)rowc * FD;
    const int kks = tid >> 4, js = (tid & 15) * 4; // B staging coords

    float4 bia = *(const float4*)&bm[tc * 4];
    float acc[4][4];
#pragma unroll
    for (int rr = 0; rr < 4; ++rr) { acc[rr][0] = bia.x; acc[rr][1] = bia.y; acc[rr][2] = bia.z; acc[rr][3] = bia.w; }

    for (int ks = 0; ks < 4; ++ks) {
        int k0 = ks * 16;
        __syncthreads();
        float4 av = *(const float4*)(arow + k0 + qs * 4);
        At[qs * 4 + 0][ms] = av.x; At[qs * 4 + 1][ms] = av.y;
        At[qs * 4 + 2][ms] = av.z; At[qs * 4 + 3][ms] = av.w;
        *(float4*)&Bt[kks][js] = *(const float4*)&Wm[(k0 + kks) * FD + js];
        __syncthreads();
#pragma unroll
        for (int k = 0; k < 16; ++k) {
            float4 a = *(const float4*)&At[k][tr * 4];
            float4 b = *(const float4*)&Bt[k][tc * 4];
            float as[4] = {a.x, a.y, a.z, a.w};
            float bs[4] = {b.x, b.y, b.z, b.w};
#pragma unroll
            for (int rr = 0; rr < 4; ++rr)
#pragma unroll
                for (int cc = 0; cc < 4; ++cc) acc[rr][cc] += as[rr] * bs[cc];
        }
    }
#pragma unroll
    for (int rr = 0; rr < 4; ++rr) {
        int r = tr * 4 + rr;
        if (n0 + r < N) {
            float4 o = make_float4(acc[rr][0], acc[rr][1], acc[rr][2], acc[rr][3]);
            *(float4*)&p[(size_t)(n0 + r) * FD + tc * 4] = o;
        }
    }
}

// K2: agg[n] = lrelu(max over in-edges of p[src]); empty -> 0.  16 thr/node.
__global__ void k_agg(const float4* __restrict__ p4, const int* __restrict__ off,
                      const int* __restrict__ endp, const int* __restrict__ esrc,
                      float4* __restrict__ agg4, int N)
{
    int tid = threadIdx.x;
    int q = tid & 15;
    int n = blockIdx.x * 16 + (tid >> 4);
    if (n >= N) return;
    int j0 = off[n], j1 = endp[n];
    float4 m = make_float4(-__builtin_inff(), -__builtin_inff(),
                           -__builtin_inff(), -__builtin_inff());
    int j = j0;
    for (; j + 1 < j1; j += 2) {
        int s0 = esrc[j], s1 = esrc[j + 1];
        float4 v0 = p4[(size_t)s0 * 16 + q];
        float4 v1 = p4[(size_t)s1 * 16 + q];
        m.x = fmaxf(m.x, v0.x); m.y = fmaxf(m.y, v0.y);
        m.z = fmaxf(m.z, v0.z); m.w = fmaxf(m.w, v0.w);
        m.x = fmaxf(m.x, v1.x); m.y = fmaxf(m.y, v1.y);
        m.z = fmaxf(m.z, v1.z); m.w = fmaxf(m.w, v1.w);
    }
    if (j < j1) {
        int s0 = esrc[j];
        float4 v0 = p4[(size_t)s0 * 16 + q];
        m.x = fmaxf(m.x, v0.x); m.y = fmaxf(m.y, v0.y);
        m.z = fmaxf(m.z, v0.z); m.w = fmaxf(m.w, v0.w);
    }
    float4 o;
    if (j0 == j1) o = make_float4(0.f, 0.f, 0.f, 0.f);
    else { o.x = lrelu(m.x); o.y = lrelu(m.y); o.z = lrelu(m.z); o.w = lrelu(m.w); }
    agg4[(size_t)n * 16 + q] = o;
}

// K3: tiled fused node kernel.
// x' = lrelu([x,xg_b,agg] @ Wa + ba) + x ; gate + per-graph max ; feat = lrelu(x' @ Wfeat + bf)
__global__ void k_node(const float* __restrict__ x_in, float* __restrict__ x_out,
                       const float* __restrict__ xg, const int* __restrict__ batch,
                       const float* __restrict__ agg,
                       const float* __restrict__ Wa, const float* __restrict__ ba,
                       const float* __restrict__ Wgate, const float* __restrict__ bgate,
                       const float* __restrict__ Wfeat, const float* __restrict__ bfeat,
                       float* __restrict__ gate_out, float* __restrict__ feat_out,
                       unsigned* __restrict__ gmax_enc, int N)
{
    __shared__ float At[16][68];
    __shared__ float Bt[16][64];
    __shared__ float Xp[64][65];   // x' tile for the feat GEMM
    __shared__ unsigned lmax[16];

    const int tid = threadIdx.x;
    const int tr = tid >> 4, tc = tid & 15;
    const int n0 = blockIdx.x * 64;
    if (tid < 16) lmax[tid] = 0u;

    // staging coords
    const int ms = tid >> 2, qs = tid & 3;
    const int rowc = min(n0 + ms, N - 1);
    const float* xrow = x_in + (size_t)rowc * FD;
    const float* grow = xg + (size_t)batch[rowc] * FD;
    const float* arow = agg + (size_t)rowc * FD;
    const int kks = tid >> 4, js = (tid & 15) * 4;

    float4 bia = *(const float4*)&ba[tc * 4];
    float acc[4][4];
#pragma unroll
    for (int rr = 0; rr < 4; ++rr) { acc[rr][0] = bia.x; acc[rr][1] = bia.y; acc[rr][2] = bia.z; acc[rr][3] = bia.w; }

    // ---- main GEMM: z[64x192] @ Wa[192x64] ----
    for (int ks = 0; ks < 12; ++ks) {
        int k0 = ks * 16;
        const float* srow = (k0 < 64) ? xrow : (k0 < 128) ? grow : arow;
        __syncthreads();
        float4 av = *(const float4*)(srow + (k0 & 63) + qs * 4);
        At[qs * 4 + 0][ms] = av.x; At[qs * 4 + 1][ms] = av.y;
        At[qs * 4 + 2][ms] = av.z; At[qs * 4 + 3][ms] = av.w;
        *(float4*)&Bt[kks][js] = *(const float4*)&Wa[(k0 + kks) * FD + js];
        __syncthreads();
#pragma unroll
        for (int k = 0; k < 16; ++k) {
            float4 a = *(const float4*)&At[k][tr * 4];
            float4 b = *(const float4*)&Bt[k][tc * 4];
            float as[4] = {a.x, a.y, a.z, a.w};
            float bs[4] = {b.x, b.y, b.z, b.w};
#pragma unroll
            for (int rr = 0; rr < 4; ++rr)
#pragma unroll
                for (int cc = 0; cc < 4; ++cc) acc[rr][cc] += as[rr] * bs[cc];
        }
    }

    // ---- epilogue 1: x' = lrelu(acc) + x ; store; gate partial ----
    float4 wg = *(const float4*)&Wgate[tc * 4];
    float gpart[4];
#pragma unroll
    for (int rr = 0; rr < 4; ++rr) {
        int r = tr * 4 + rr;
        float4 xv = *(const float4*)&x_in[(size_t)min(n0 + r, N - 1) * FD + tc * 4];
        float v0 = lrelu(acc[rr][0]) + xv.x;
        float v1 = lrelu(acc[rr][1]) + xv.y;
        float v2 = lrelu(acc[rr][2]) + xv.z;
        float v3 = lrelu(acc[rr][3]) + xv.w;
        Xp[r][tc * 4 + 0] = v0; Xp[r][tc * 4 + 1] = v1;
        Xp[r][tc * 4 + 2] = v2; Xp[r][tc * 4 + 3] = v3;
        if (n0 + r < N) {
            float4 o = make_float4(v0, v1, v2, v3);
            *(float4*)&x_out[(size_t)(n0 + r) * FD + tc * 4] = o;
        }
        gpart[rr] = v0 * wg.x + v1 * wg.y + v2 * wg.z + v3 * wg.w;
    }
    // reduce gate across the 16 tc lanes (consecutive lanes within wave)
#pragma unroll
    for (int rr = 0; rr < 4; ++rr) {
        float g = gpart[rr];
        g += __shfl_xor(g, 1); g += __shfl_xor(g, 2);
        g += __shfl_xor(g, 4); g += __shfl_xor(g, 8);
        if (tc == 0) {
            int r = tr * 4 + rr;
            if (n0 + r < N) {
                float gv = g + bgate[0];
                gate_out[n0 + r] = gv;
                atomicMax(&lmax[batch[n0 + r]], enc_f32(gv));
            }
        }
    }

    // ---- feat GEMM: x'[64x64] @ Wfeat[64x64] ----
    float4 bif = *(const float4*)&bfeat[tc * 4];
    float acc2[4][4];
#pragma unroll
    for (int rr = 0; rr < 4; ++rr) { acc2[rr][0] = bif.x; acc2[rr][1] = bif.y; acc2[rr][2] = bif.z; acc2[rr][3] = bif.w; }

    for (int ks = 0; ks < 4; ++ks) {
        int k0 = ks * 16;
        __syncthreads();   // Bt free to overwrite; Xp visible (first iter)
        *(float4*)&Bt[kks][js] = *(const float4*)&Wfeat[(k0 + kks) * FD + js];
        __syncthreads();
#pragma unroll
        for (int k = 0; k < 16; ++k) {
            float as[4];
#pragma unroll
            for (int rr = 0; rr < 4; ++rr) as[rr] = Xp[tr * 4 + rr][k0 + k];
            float4 b = *(const float4*)&Bt[k][tc * 4];
            float bs[4] = {b.x, b.y, b.z, b.w};
#pragma unroll
            for (int rr = 0; rr < 4; ++rr)
#pragma unroll
                for (int cc = 0; cc < 4; ++cc) acc2[rr][cc] += as[rr] * bs[cc];
        }
    }
#pragma unroll
    for (int rr = 0; rr < 4; ++rr) {
        int r = tr * 4 + rr;
        if (n0 + r < N) {
            float4 o = make_float4(lrelu(acc2[rr][0]), lrelu(acc2[rr][1]),
                                   lrelu(acc2[rr][2]), lrelu(acc2[rr][3]));
            *(float4*)&feat_out[(size_t)(n0 + r) * FD + tc * 4] = o;
        }
    }
    __syncthreads();
    if (tid < 16 && lmax[tid] != 0u) atomicMax(&gmax_enc[tid], lmax[tid]);
}

// K4: per-graph  sum_e = sum exp(gate-gmax),  V = sum exp(gate-gmax)*feat
__global__ void k_pool(const float* __restrict__ gate, const float* __restrict__ feat,
                       const int* __restrict__ batch, const unsigned* __restrict__ gmax_enc,
                       float* __restrict__ sum_e, float* __restrict__ Vv, int N)
{
    int gid = blockIdx.x * blockDim.x + threadIdx.x;
    int wave = gid >> 6;
    int lane = threadIdx.x & 63;
    int nwaves = (gridDim.x * blockDim.x) >> 6;
    int chunk = (N + nwaves - 1) / nwaves;
    int n0 = wave * chunk;
    int n1 = min(N, n0 + chunk);
    if (n0 >= n1) return;
    int gcur = batch[n0];
    float gm = dec_f32(gmax_enc[gcur]);
    float accv = 0.f, acce = 0.f;
    for (int n = n0; n < n1; ++n) {
        int g = batch[n];
        if (g != gcur) {
            atomicAdd(&Vv[gcur * FD + lane], accv);
            if (lane == 0) atomicAdd(&sum_e[gcur], acce);
            gcur = g;
            gm = dec_f32(gmax_enc[g]);
            accv = 0.f; acce = 0.f;
        }
        float e = __expf(gate[n] - gm);
        accv += e * feat[(size_t)n * FD + lane];
        acce += e;
    }
    atomicAdd(&Vv[gcur * FD + lane], accv);
    if (lane == 0) atomicAdd(&sum_e[gcur], acce);
}

// K5: x_global' = lrelu([V/sum_e, x_global] @ Wt + bt) + x_global
// one block (64 threads) per graph
__global__ void k_global(const float* __restrict__ xg_in, float* __restrict__ xg_out,
                         const float* __restrict__ Vv, const float* __restrict__ sum_e,
                         const float* __restrict__ Wt, const float* __restrict__ bt, int NG)
{
    __shared__ float xgn[FD], xgo[FD];
    int g = blockIdx.x, j = threadIdx.x;
    xgn[j] = Vv[g * FD + j] / sum_e[g];
    xgo[j] = xg_in[g * FD + j];
    __syncthreads();
    float acc = bt[j];
    for (int k = 0; k < FD; ++k) acc += xgn[k] * Wt[k * FD + j];
    for (int k = 0; k < FD; ++k) acc += xgo[k] * Wt[(FD + k) * FD + j];
    xg_out[g * FD + j] = lrelu(acc) + xgo[j];
}

extern "C" void kernel_launch(void* const* d_in, const int* in_sizes, int n_in,
                              void* d_out, int out_size, void* d_ws, size_t ws_size,
                              hipStream_t stream)
{
    const float* x0     = (const float*)d_in[0];
    const float* xg0    = (const float*)d_in[1];
    const int*   ei     = (const int*)d_in[3];
    const int*   batch  = (const int*)d_in[4];
    const float* Wm     = (const float*)d_in[6];
    const float* bm     = (const float*)d_in[7];
    const float* Wa     = (const float*)d_in[8];
    const float* ba     = (const float*)d_in[9];
    const float* Wgate  = (const float*)d_in[10];
    const float* bgate  = (const float*)d_in[11];
    const float* Wfeat  = (const float*)d_in[12];
    const float* bfeat  = (const float*)d_in[13];
    const float* Wt     = (const float*)d_in[14];
    const float* bt     = (const float*)d_in[15];

    const int N  = in_sizes[0] / FD;
    const int E  = in_sizes[3] / 2;
    const int NG = in_sizes[1] / FD;
    const int S  = in_sizes[6] / (FD * FD);

    const int* esrc_in = ei;       // edge_index[0]
    const int* edst_in = ei + E;   // edge_index[1]

    float* x_out  = (float*)d_out;
    float* xg_out = (float*)d_out + (size_t)N * FD;

    // ---- workspace layout ----
    char* ws = (char*)d_ws;
    const size_t rowB = (size_t)N * FD * 4;
    float* agg   = (float*)ws;
    float* p     = (float*)(ws + rowB);
    float* feat  = p;
    int*   esrc  = (int*)(ws + 2 * rowB);
    int*   off   = (int*)(ws + 2 * rowB + (size_t)E * 4);
    int*   endp  = off + N;
    int*   deg   = endp + N;
    float* gate  = (float*)deg;
    int*   bsums = deg + N;
    unsigned* gmax_enc = (unsigned*)(bsums + 1024);
    float* sum_e = (float*)(gmax_enc + 64);
    float* Vv    = sum_e + 64;

    const int nb_node = (N + 255) / 256;
    const int nb_edge = (E + 255) / 256;
    const int nb_scan = (N + SCAN_BS - 1) / SCAN_BS;
    const int nb_agg  = (N + 15) / 16;
    const int nb_tile = (N + 63) / 64;

    // ---- preprocessing: CSR by dst ----
    hipMemsetAsync(deg, 0, (size_t)N * 4, stream);
    k_hist <<<nb_edge, 256, 0, stream>>>(edst_in, deg, E);
    k_scan1<<<nb_scan, SCAN_BS, 0, stream>>>(deg, off, bsums, N);
    k_scan2<<<1, SCAN_BS, 0, stream>>>(bsums, nb_scan);
    k_scan3<<<nb_node, 256, 0, stream>>>(off, bsums, endp, N);
    k_place<<<nb_edge, 256, 0, stream>>>(esrc_in, edst_in, endp, esrc, E);

    const float* x_in  = x0;
    const float* xg_in = xg0;

    for (int i = 0; i < S; ++i) {
        hipMemsetAsync(gmax_enc, 0, (64 + 64 + 1024) * 4, stream);
        k_proj<<<nb_tile, 256, 0, stream>>>(x_in, Wm + i * FD * FD, bm + i * FD, p, N);
        k_agg <<<nb_agg, 256, 0, stream>>>((const float4*)p, off, endp, esrc,
                                           (float4*)agg, N);
        k_node<<<nb_tile, 256, 0, stream>>>(x_in, x_out, xg_in, batch, agg,
                                            Wa + (size_t)i * 192 * FD, ba + i * FD,
                                            Wgate + i * FD, bgate + i,
                                            Wfeat + i * FD * FD, bfeat + i * FD,
                                            gate, feat, gmax_enc, N);
        k_pool<<<256, 256, 0, stream>>>(gate, feat, batch, gmax_enc, sum_e, Vv, N);
        k_global<<<NG, FD, 0, stream>>>(xg_in, xg_out, Vv, sum_e,
                                        Wt + (size_t)i * 2 * FD * FD, bt + i * FD, NG);
        x_in  = x_out;
        xg_in = xg_out;
    }
}

// Round 5
// 1221.267 us; speedup vs baseline: 2.4440x; 2.4440x over previous
//
#include <hip/hip_runtime.h>

#define FD 64           // feature dim D = A = G = 64
#define NSLOPE 0.01f
#define SCAN_BS 1024

__device__ __forceinline__ float lrelu(float v) { return v > 0.f ? v : NSLOPE * v; }

__device__ __forceinline__ unsigned enc_f32(float f) {
    unsigned u = __float_as_uint(f);
    return (u & 0x80000000u) ? ~u : (u | 0x80000000u);
}
__device__ __forceinline__ float dec_f32(unsigned u) {
    return (u & 0x80000000u) ? __uint_as_float(u & 0x7FFFFFFFu) : __uint_as_float(~u);
}

// ---------------- preprocessing: CSR by dst (once per launch) ----------------

__global__ void k_hist(const int* __restrict__ dst, int* __restrict__ deg, int E)
{
    int e = blockIdx.x * blockDim.x + threadIdx.x;
    if (e < E) atomicAdd(&deg[dst[e]], 1);
}

__global__ void k_scan1(const int* __restrict__ deg, int* __restrict__ off,
                        int* __restrict__ bsums, int N)
{
    __shared__ int tmp[SCAN_BS];
    int t = threadIdx.x, b = blockIdx.x;
    int i = b * SCAN_BS + t;
    int v = (i < N) ? deg[i] : 0;
    tmp[t] = v;
    __syncthreads();
    for (int d = 1; d < SCAN_BS; d <<= 1) {
        int add = (t >= d) ? tmp[t - d] : 0;
        __syncthreads();
        tmp[t] += add;
        __syncthreads();
    }
    if (i < N) off[i] = tmp[t] - v;
    if (t == SCAN_BS - 1) bsums[b] = tmp[t];
}

__global__ void k_scan2(int* __restrict__ bsums, int nb)
{
    __shared__ int tmp[SCAN_BS];
    int t = threadIdx.x;
    int v = (t < nb) ? bsums[t] : 0;
    tmp[t] = v;
    __syncthreads();
    for (int d = 1; d < SCAN_BS; d <<= 1) {
        int add = (t >= d) ? tmp[t - d] : 0;
        __syncthreads();
        tmp[t] += add;
        __syncthreads();
    }
    if (t < nb) bsums[t] = tmp[t] - v;
}

__global__ void k_scan3(int* __restrict__ off, const int* __restrict__ bsums,
                        int* __restrict__ cursor, int N)
{
    int i = blockIdx.x * blockDim.x + threadIdx.x;
    if (i < N) {
        int o = off[i] + bsums[i >> 10];
        off[i] = o;
        cursor[i] = o;
    }
}

__global__ void k_place(const int* __restrict__ src, const int* __restrict__ dst,
                        int* __restrict__ cursor, int* __restrict__ esrc, int E)
{
    int e = blockIdx.x * blockDim.x + threadIdx.x;
    if (e >= E) return;
    int pos = atomicAdd(&cursor[dst[e]], 1);
    esrc[pos] = src[e];
}

// ---------------- per-step kernels ----------------

// K1: p = x @ Wm + bm   (naive node-per-thread; weight loads are lane-uniform -> SMEM)
__global__ void k_proj(const float* __restrict__ x, const float* __restrict__ Wm,
                       const float* __restrict__ bm, float* __restrict__ p, int N)
{
    int n = blockIdx.x * blockDim.x + threadIdx.x;
    if (n >= N) return;
    const float* xr = x + (size_t)n * FD;
    float acc[FD];
#pragma unroll
    for (int j = 0; j < FD; ++j) acc[j] = bm[j];
    for (int kt = 0; kt < FD / 8; ++kt) {
        float4 a = *(const float4*)(xr + kt * 8);
        float4 b = *(const float4*)(xr + kt * 8 + 4);
        float z8[8] = {a.x, a.y, a.z, a.w, b.x, b.y, b.z, b.w};
#pragma unroll
        for (int kk = 0; kk < 8; ++kk) {
            const float* wrow = Wm + (kt * 8 + kk) * FD;
#pragma unroll
            for (int j = 0; j < FD; ++j) acc[j] += z8[kk] * wrow[j];
        }
    }
    float* pr = p + (size_t)n * FD;
#pragma unroll
    for (int j = 0; j < FD; ++j) pr[j] = acc[j];
}

// K2: agg[n] = lrelu(max over in-edges of p[src]); empty -> 0.  16 thr/node.
__global__ void k_agg(const float4* __restrict__ p4, const int* __restrict__ off,
                      const int* __restrict__ endp, const int* __restrict__ esrc,
                      float4* __restrict__ agg4, int N)
{
    int tid = threadIdx.x;
    int q = tid & 15;
    int n = blockIdx.x * 16 + (tid >> 4);
    if (n >= N) return;
    int j0 = off[n], j1 = endp[n];
    float4 m = make_float4(-__builtin_inff(), -__builtin_inff(),
                           -__builtin_inff(), -__builtin_inff());
    int j = j0;
    for (; j + 1 < j1; j += 2) {
        int s0 = esrc[j], s1 = esrc[j + 1];
        float4 v0 = p4[(size_t)s0 * 16 + q];
        float4 v1 = p4[(size_t)s1 * 16 + q];
        m.x = fmaxf(m.x, v0.x); m.y = fmaxf(m.y, v0.y);
        m.z = fmaxf(m.z, v0.z); m.w = fmaxf(m.w, v0.w);
        m.x = fmaxf(m.x, v1.x); m.y = fmaxf(m.y, v1.y);
        m.z = fmaxf(m.z, v1.z); m.w = fmaxf(m.w, v1.w);
    }
    if (j < j1) {
        int s0 = esrc[j];
        float4 v0 = p4[(size_t)s0 * 16 + q];
        m.x = fmaxf(m.x, v0.x); m.y = fmaxf(m.y, v0.y);
        m.z = fmaxf(m.z, v0.z); m.w = fmaxf(m.w, v0.w);
    }
    float4 o;
    if (j0 == j1) o = make_float4(0.f, 0.f, 0.f, 0.f);
    else { o.x = lrelu(m.x); o.y = lrelu(m.y); o.z = lrelu(m.z); o.w = lrelu(m.w); }
    agg4[(size_t)n * 16 + q] = o;
}

// K3 (naive, node-per-thread): x' = lrelu([x,xg_b,agg] @ Wa + ba) + x ; gate ;
//    per-graph gate max ; feat = lrelu(x' @ Wfeat + bfeat)
__global__ void k_node(const float* __restrict__ x_in, float* __restrict__ x_out,
                       const float* __restrict__ xg, const int* __restrict__ batch,
                       const float* __restrict__ agg,
                       const float* __restrict__ Wa, const float* __restrict__ ba,
                       const float* __restrict__ Wgate, const float* __restrict__ bgate,
                       const float* __restrict__ Wfeat, const float* __restrict__ bfeat,
                       float* __restrict__ gate_out, float* __restrict__ feat_out,
                       unsigned* __restrict__ gmax_enc, int N)
{
    __shared__ unsigned lmax[16];
    int tid = threadIdx.x;
    if (tid < 16) lmax[tid] = 0u;
    __syncthreads();
    int n = blockIdx.x * blockDim.x + tid;
    if (n < N) {
        int g = batch[n];
        const float* xr  = x_in + (size_t)n * FD;
        const float* xgr = xg + (size_t)g * FD;
        const float* ar  = agg + (size_t)n * FD;
        float acc[FD];
#pragma unroll
        for (int j = 0; j < FD; ++j) acc[j] = ba[j];
        // z segment 0: x
        for (int kt = 0; kt < 8; ++kt) {
            float4 a = *(const float4*)(xr + kt * 8);
            float4 b = *(const float4*)(xr + kt * 8 + 4);
            float z8[8] = {a.x, a.y, a.z, a.w, b.x, b.y, b.z, b.w};
#pragma unroll
            for (int kk = 0; kk < 8; ++kk) {
                const float* wrow = Wa + (kt * 8 + kk) * FD;
#pragma unroll
                for (int j = 0; j < FD; ++j) acc[j] += z8[kk] * wrow[j];
            }
        }
        // z segment 1: x_global[batch]
        for (int kt = 0; kt < 8; ++kt) {
            float4 a = *(const float4*)(xgr + kt * 8);
            float4 b = *(const float4*)(xgr + kt * 8 + 4);
            float z8[8] = {a.x, a.y, a.z, a.w, b.x, b.y, b.z, b.w};
#pragma unroll
            for (int kk = 0; kk < 8; ++kk) {
                const float* wrow = Wa + (64 + kt * 8 + kk) * FD;
#pragma unroll
                for (int j = 0; j < FD; ++j) acc[j] += z8[kk] * wrow[j];
            }
        }
        // z segment 2: agg
        for (int kt = 0; kt < 8; ++kt) {
            float4 a = *(const float4*)(ar + kt * 8);
            float4 b = *(const float4*)(ar + kt * 8 + 4);
            float z8[8] = {a.x, a.y, a.z, a.w, b.x, b.y, b.z, b.w};
#pragma unroll
            for (int kk = 0; kk < 8; ++kk) {
                const float* wrow = Wa + (128 + kt * 8 + kk) * FD;
#pragma unroll
                for (int j = 0; j < FD; ++j) acc[j] += z8[kk] * wrow[j];
            }
        }
        // finish node update + gate
        float gv = bgate[0];
        float* xo = x_out + (size_t)n * FD;
#pragma unroll
        for (int j = 0; j < FD; ++j) {
            float v = lrelu(acc[j]) + xr[j];
            xo[j] = v;
            gv += v * Wgate[j];
        }
        gate_out[n] = gv;
        atomicMax(&lmax[g], enc_f32(gv));
        // feat = lrelu(x' @ Wfeat + bfeat)
        float acc2[FD];
#pragma unroll
        for (int j = 0; j < FD; ++j) acc2[j] = bfeat[j];
        for (int kt = 0; kt < 8; ++kt) {
            float4 a = *(const float4*)(xo + kt * 8);
            float4 b = *(const float4*)(xo + kt * 8 + 4);
            float z8[8] = {a.x, a.y, a.z, a.w, b.x, b.y, b.z, b.w};
#pragma unroll
            for (int kk = 0; kk < 8; ++kk) {
                const float* wrow = Wfeat + (kt * 8 + kk) * FD;
#pragma unroll
                for (int j = 0; j < FD; ++j) acc2[j] += z8[kk] * wrow[j];
            }
        }
        float* fo = feat_out + (size_t)n * FD;
#pragma unroll
        for (int j = 0; j < FD; ++j) fo[j] = lrelu(acc2[j]);
    }
    __syncthreads();
    if (tid < 16 && lmax[tid] != 0u) atomicMax(&gmax_enc[tid], lmax[tid]);
}

// K4: per-graph  sum_e = sum exp(gate-gmax),  V = sum exp(gate-gmax)*feat
__global__ void k_pool(const float* __restrict__ gate, const float* __restrict__ feat,
                       const int* __restrict__ batch, const unsigned* __restrict__ gmax_enc,
                       float* __restrict__ sum_e, float* __restrict__ Vv, int N)
{
    int gid = blockIdx.x * blockDim.x + threadIdx.x;
    int wave = gid >> 6;
    int lane = threadIdx.x & 63;
    int nwaves = (gridDim.x * blockDim.x) >> 6;
    int chunk = (N + nwaves - 1) / nwaves;
    int n0 = wave * chunk;
    int n1 = min(N, n0 + chunk);
    if (n0 >= n1) return;
    int gcur = batch[n0];
    float gm = dec_f32(gmax_enc[gcur]);
    float accv = 0.f, acce = 0.f;
    for (int n = n0; n < n1; ++n) {
        int g = batch[n];
        if (g != gcur) {
            atomicAdd(&Vv[gcur * FD + lane], accv);
            if (lane == 0) atomicAdd(&sum_e[gcur], acce);
            gcur = g;
            gm = dec_f32(gmax_enc[g]);
            accv = 0.f; acce = 0.f;
        }
        float e = __expf(gate[n] - gm);
        accv += e * feat[(size_t)n * FD + lane];
        acce += e;
    }
    atomicAdd(&Vv[gcur * FD + lane], accv);
    if (lane == 0) atomicAdd(&sum_e[gcur], acce);
}

// K5: x_global' = lrelu([V/sum_e, x_global] @ Wt + bt) + x_global
// one block (64 threads) per graph
__global__ void k_global(const float* __restrict__ xg_in, float* __restrict__ xg_out,
                         const float* __restrict__ Vv, const float* __restrict__ sum_e,
                         const float* __restrict__ Wt, const float* __restrict__ bt, int NG)
{
    __shared__ float xgn[FD], xgo[FD];
    int g = blockIdx.x, j = threadIdx.x;
    xgn[j] = Vv[g * FD + j] / sum_e[g];
    xgo[j] = xg_in[g * FD + j];
    __syncthreads();
    float acc = bt[j];
    for (int k = 0; k < FD; ++k) acc += xgn[k] * Wt[k * FD + j];
    for (int k = 0; k < FD; ++k) acc += xgo[k] * Wt[(FD + k) * FD + j];
    xg_out[g * FD + j] = lrelu(acc) + xgo[j];
}

extern "C" void kernel_launch(void* const* d_in, const int* in_sizes, int n_in,
                              void* d_out, int out_size, void* d_ws, size_t ws_size,
                              hipStream_t stream)
{
    const float* x0     = (const float*)d_in[0];
    const float* xg0    = (const float*)d_in[1];
    const int*   ei     = (const int*)d_in[3];
    const int*   batch  = (const int*)d_in[4];
    const float* Wm     = (const float*)d_in[6];
    const float* bm     = (const float*)d_in[7];
    const float* Wa     = (const float*)d_in[8];
    const float* ba     = (const float*)d_in[9];
    const float* Wgate  = (const float*)d_in[10];
    const float* bgate  = (const float*)d_in[11];
    const float* Wfeat  = (const float*)d_in[12];
    const float* bfeat  = (const float*)d_in[13];
    const float* Wt     = (const float*)d_in[14];
    const float* bt     = (const float*)d_in[15];

    const int N  = in_sizes[0] / FD;
    const int E  = in_sizes[3] / 2;
    const int NG = in_sizes[1] / FD;
    const int S  = in_sizes[6] / (FD * FD);

    const int* esrc_in = ei;       // edge_index[0]
    const int* edst_in = ei + E;   // edge_index[1]

    float* x_out  = (float*)d_out;
    float* xg_out = (float*)d_out + (size_t)N * FD;

    // ---- workspace layout ----
    char* ws = (char*)d_ws;
    const size_t rowB = (size_t)N * FD * 4;
    float* agg   = (float*)ws;
    float* p     = (float*)(ws + rowB);
    float* feat  = p;
    int*   esrc  = (int*)(ws + 2 * rowB);
    int*   off   = (int*)(ws + 2 * rowB + (size_t)E * 4);
    int*   endp  = off + N;
    int*   deg   = endp + N;
    float* gate  = (float*)deg;
    int*   bsums = deg + N;
    unsigned* gmax_enc = (unsigned*)(bsums + 1024);
    float* sum_e = (float*)(gmax_enc + 64);
    float* Vv    = sum_e + 64;

    const int nb_node = (N + 255) / 256;
    const int nb_edge = (E + 255) / 256;
    const int nb_scan = (N + SCAN_BS - 1) / SCAN_BS;
    const int nb_agg  = (N + 15) / 16;

    // ---- preprocessing: CSR by dst ----
    hipMemsetAsync(deg, 0, (size_t)N * 4, stream);
    k_hist <<<nb_edge, 256, 0, stream>>>(edst_in, deg, E);
    k_scan1<<<nb_scan, SCAN_BS, 0, stream>>>(deg, off, bsums, N);
    k_scan2<<<1, SCAN_BS, 0, stream>>>(bsums, nb_scan);
    k_scan3<<<nb_node, 256, 0, stream>>>(off, bsums, endp, N);
    k_place<<<nb_edge, 256, 0, stream>>>(esrc_in, edst_in, endp, esrc, E);

    const float* x_in  = x0;
    const float* xg_in = xg0;

    for (int i = 0; i < S; ++i) {
        hipMemsetAsync(gmax_enc, 0, (64 + 64 + 1024) * 4, stream);
        k_proj<<<nb_node, 256, 0, stream>>>(x_in, Wm + i * FD * FD, bm + i * FD, p, N);
        k_agg <<<nb_agg, 256, 0, stream>>>((const float4*)p, off, endp, esrc,
                                           (float4*)agg, N);
        k_node<<<nb_node, 256, 0, stream>>>(x_in, x_out, xg_in, batch, agg,
                                            Wa + (size_t)i * 192 * FD, ba + i * FD,
                                            Wgate + i * FD, bgate + i,
                                            Wfeat + i * FD * FD, bfeat + i * FD,
                                            gate, feat, gmax_enc, N);
        k_pool<<<256, 256, 0, stream>>>(gate, feat, batch, gmax_enc, sum_e, Vv, N);
        k_global<<<NG, FD, 0, stream>>>(xg_in, xg_out, Vv, sum_e,
                                        Wt + (size_t)i * 2 * FD * FD, bt + i * FD, NG);
        x_in  = x_out;
        xg_in = xg_out;
    }
}